// Round 3
// baseline (193.587 us; speedup 1.0000x reference)
//
#include <hip/hip_runtime.h>

#define BB 4096
#define TT 10
#define SS 301
#define HH 5
#define OO 3

__device__ __forceinline__ float rcp_hw(float x) { return __builtin_amdgcn_rcpf(x); }

// Eigen-style minimax rational tanh on clamped |x|<=9 (rel err ~1e-6).
// p: odd deg-13 numerator, q: even deg-6 denominator, both in u = x^2.
#define TA1  4.89352455891786e-03f
#define TA3  6.37261928875436e-04f
#define TA5  1.48572235717979e-05f
#define TA7  5.12229709037114e-08f
#define TA9  -8.60467152213735e-11f
#define TA11 2.00018790482477e-13f
#define TA13 -2.76076847742355e-16f
#define TB0  4.89352518554385e-03f
#define TB2  2.26843463243900e-03f
#define TB4  1.18534705686654e-04f
#define TB6  1.19825839466702e-06f

__global__ __launch_bounds__(256) void gru_kernel(
    const float* __restrict__ x,
    const float* __restrict__ w_ih,
    const float* __restrict__ w_hh,
    const float* __restrict__ b_ih,
    const float* __restrict__ b_hh,
    const float* __restrict__ fc_w,
    const float* __restrict__ fc_b,
    float* __restrict__ out)
{
    const int n = blockIdx.x * blockDim.x + threadIdx.x;
    const int b = n / SS;
    const int s = n - b * SS;
    if (b >= BB) return;

    // --- Pin polynomial constants into registers ONCE. ---
    // v_fma_f32 is VOP3: literals are illegal, and only 1 SGPR read per
    // vector instr. Without pinning, the compiler rematerializes these 32-bit
    // literals via v_mov per use (~12 VALU issues per activation = the R2
    // regression). "+s" pins to SGPR; the two chain-start partners go to
    // VGPRs ("+v") so no FMA needs two SGPR operands.
    float cA13 = TA13, cA9 = TA9, cA7 = TA7, cA5 = TA5, cA3 = TA3, cA1 = TA1;
    float cB6 = TB6, cB2 = TB2, cB0 = TB0, cLo = -9.0f, cHi = 9.0f;
    asm volatile("" : "+s"(cA13), "+s"(cA9), "+s"(cA7), "+s"(cA5), "+s"(cA3), "+s"(cA1));
    asm volatile("" : "+s"(cB6), "+s"(cB2), "+s"(cB0), "+s"(cLo), "+s"(cHi));
    float vA11 = TA11, vB4 = TB4;
    asm volatile("" : "+v"(vA11), "+v"(vB4));

    // Shared rational core: returns p(u)*x and 1/q(u).
    // tanh(x)            = px * ir
    // sigmoid(2x)        = fma(px, 0.5*ir, 0.5)   [x is the PRE-HALVED preact]
    #define POLY_CORE(XX, PX, IR)                          \
        do {                                               \
            float xc_ = fminf(fmaxf((XX), cLo), cHi);      \
            float u_  = xc_ * xc_;                         \
            float p_  = __fmaf_rn(cA13, u_, vA11);         \
            p_ = __fmaf_rn(p_, u_, cA9);                   \
            p_ = __fmaf_rn(p_, u_, cA7);                   \
            p_ = __fmaf_rn(p_, u_, cA5);                   \
            p_ = __fmaf_rn(p_, u_, cA3);                   \
            p_ = __fmaf_rn(p_, u_, cA1);                   \
            (PX) = p_ * xc_;                               \
            float q_ = __fmaf_rn(cB6, u_, vB4);            \
            q_ = __fmaf_rn(q_, u_, cB2);                   \
            q_ = __fmaf_rn(q_, u_, cB0);                   \
            (IR) = rcp_hw(q_);                             \
        } while (0)

    // Wave-uniform weights: scalar loads into SGPRs.
    // r,z rows (g < 2H) are PRE-HALVED so their preacts are a/2, feeding the
    // sigmoid identity sigma(a) = 0.5 + 0.5*tanh(a/2).
    float wih[3 * HH];
    float whh[3 * HH][HH];
    float brz[2 * HH];   // 0.5*(b_ih + b_hh) for r,z gates
    float bin[HH];       // b_ih for n gate (outside r*)
    float bhn[HH];       // b_hh for n gate (inside r*)

    #pragma unroll
    for (int g = 0; g < 2 * HH; ++g) {
        brz[g] = 0.5f * (b_ih[g] + b_hh[g]);
        wih[g] = 0.5f * w_ih[g];   // I == 1
        #pragma unroll
        for (int k = 0; k < HH; ++k) whh[g][k] = 0.5f * w_hh[g * HH + k];
    }
    #pragma unroll
    for (int j = 0; j < HH; ++j) {
        const int g = 2 * HH + j;
        bin[j] = b_ih[g];
        bhn[j] = b_hh[g];
        wih[g] = w_ih[g];
        #pragma unroll
        for (int k = 0; k < HH; ++k) whh[g][k] = w_hh[g * HH + k];
    }

    // Preload all 10 inputs for this sample (coalesced across the wave per t).
    float xt[TT];
    const float* xp = x + (size_t)b * (TT * SS) + s;
    #pragma unroll
    for (int t = 0; t < TT; ++t) xt[t] = xp[t * SS];

    float h[HH];
    #pragma unroll
    for (int j = 0; j < HH; ++j) h[j] = 0.0f;

    #pragma unroll
    for (int t = 0; t < TT; ++t) {
        float hn[HH];
        #pragma unroll
        for (int j = 0; j < HH; ++j) {
            float ar  = __fmaf_rn(xt[t], wih[j],          brz[j]);       // half-preact
            float az  = __fmaf_rn(xt[t], wih[HH + j],     brz[HH + j]);  // half-preact
            float ain = __fmaf_rn(xt[t], wih[2 * HH + j], bin[j]);
            float ahn = bhn[j];
            #pragma unroll
            for (int k = 0; k < HH; ++k) {
                ar  = __fmaf_rn(whh[j][k],          h[k], ar);
                az  = __fmaf_rn(whh[HH + j][k],     h[k], az);
                ahn = __fmaf_rn(whh[2 * HH + j][k], h[k], ahn);
            }
            float rpx, rir, zpx, zir;
            POLY_CORE(ar, rpx, rir);
            POLY_CORE(az, zpx, zir);
            float r = __fmaf_rn(rpx, 0.5f * rir, 0.5f);   // sigmoid
            float z = __fmaf_rn(zpx, 0.5f * zir, 0.5f);   // sigmoid
            float npx, nir;
            POLY_CORE(__fmaf_rn(r, ahn, ain), npx, nir);
            float nv = npx * nir;                          // tanh
            // (1-z)*nv + z*h = z*(h - nv) + nv
            hn[j] = __fmaf_rn(z, h[j] - nv, nv);
        }
        #pragma unroll
        for (int j = 0; j < HH; ++j) h[j] = hn[j];
    }

    // y = fc(h); out[(b*O + o)*S + s]
    float* op = out + (size_t)b * (OO * SS) + s;
    #pragma unroll
    for (int o = 0; o < OO; ++o) {
        float y = fc_b[o];
        #pragma unroll
        for (int k = 0; k < HH; ++k) y = __fmaf_rn(fc_w[o * HH + k], h[k], y);
        op[o * SS] = y;
    }
}

extern "C" void kernel_launch(void* const* d_in, const int* in_sizes, int n_in,
                              void* d_out, int out_size, void* d_ws, size_t ws_size,
                              hipStream_t stream) {
    const float* x    = (const float*)d_in[0];
    const float* w_ih = (const float*)d_in[1];
    const float* w_hh = (const float*)d_in[2];
    const float* b_ih = (const float*)d_in[3];
    const float* b_hh = (const float*)d_in[4];
    const float* fc_w = (const float*)d_in[5];
    const float* fc_b = (const float*)d_in[6];
    float* out = (float*)d_out;

    const int N = BB * SS;                 // 1,232,896
    const int block = 256;
    const int grid = (N + block - 1) / block;  // 4816 exactly
    gru_kernel<<<grid, block, 0, stream>>>(x, w_ih, w_hh, b_ih, b_hh, fc_w, fc_b, out);
}

// Round 5
// 162.629 us; speedup vs baseline: 1.1904x; 1.1904x over previous
//
#include <hip/hip_runtime.h>

#define BB 4096
#define TT 10
#define SS 301
#define HH 5
#define OO 3

// Raw v_rcp_f32 (~1 ulp) instead of IEEE div sequence.
__device__ __forceinline__ float fast_rcp(float x) {
    return __builtin_amdgcn_rcpf(x);
}
__device__ __forceinline__ float sigmoidf_fast(float x) {
    // 1/(1+e^-x); rcp(inf)=0 handles the saturated tail.
    return fast_rcp(1.0f + __expf(-x));
}
// overflow-safe tanh: 1 - 2/(e^{2x}+1); e->inf gives 1, e->0 gives -1
__device__ __forceinline__ float tanhf_fast(float x) {
    return __fmaf_rn(-2.0f, fast_rcp(__expf(2.0f * x) + 1.0f), 1.0f);
}

__global__ __launch_bounds__(256) void gru_kernel(
    const float* __restrict__ x,
    const float* __restrict__ w_ih,
    const float* __restrict__ w_hh,
    const float* __restrict__ b_ih,
    const float* __restrict__ b_hh,
    const float* __restrict__ fc_w,
    const float* __restrict__ fc_b,
    float* __restrict__ out)
{
    // Two batch rows per thread: doubles independent dependency chains per
    // wave (latency hiding via ILP) at constant instructions/element.
    const int n  = blockIdx.x * blockDim.x + threadIdx.x;
    const int bp = n / SS;
    const int s  = n - bp * SS;
    if (bp >= BB / 2) return;
    const int b0 = 2 * bp;

    // Wave-uniform weights: compiler emits scalar loads into SGPRs.
    float wih[3 * HH];
    float whh[3 * HH][HH];
    float brz[2 * HH];   // merged b_ih + b_hh for r,z gates
    float bin[HH];       // b_ih for n gate (outside r*)
    float bhn[HH];       // b_hh for n gate (inside r*)

    #pragma unroll
    for (int g = 0; g < 2 * HH; ++g) brz[g] = b_ih[g] + b_hh[g];
    #pragma unroll
    for (int j = 0; j < HH; ++j) {
        bin[j] = b_ih[2 * HH + j];
        bhn[j] = b_hh[2 * HH + j];
    }
    #pragma unroll
    for (int g = 0; g < 3 * HH; ++g) {
        wih[g] = w_ih[g];   // I == 1
        #pragma unroll
        for (int k = 0; k < HH; ++k) whh[g][k] = w_hh[g * HH + k];
    }

    // Preload the 10 inputs for BOTH rows (each stream coalesced per t).
    float xa[TT], xb[TT];
    const float* xp = x + (size_t)b0 * (TT * SS) + s;
    #pragma unroll
    for (int t = 0; t < TT; ++t) {
        xa[t] = xp[t * SS];
        xb[t] = xp[TT * SS + t * SS];   // row b0+1
    }

    float ha[HH], hb[HH];
    #pragma unroll
    for (int j = 0; j < HH; ++j) { ha[j] = 0.0f; hb[j] = 0.0f; }

    #pragma unroll
    for (int t = 0; t < TT; ++t) {
        float na[HH], nb[HH];
        #pragma unroll
        for (int j = 0; j < HH; ++j) {
            // Stream A
            float ar_a  = __fmaf_rn(xa[t], wih[j],          brz[j]);
            float az_a  = __fmaf_rn(xa[t], wih[HH + j],     brz[HH + j]);
            float ain_a = __fmaf_rn(xa[t], wih[2 * HH + j], bin[j]);
            float ahn_a = bhn[j];
            // Stream B (independent chain, same SGPR weights)
            float ar_b  = __fmaf_rn(xb[t], wih[j],          brz[j]);
            float az_b  = __fmaf_rn(xb[t], wih[HH + j],     brz[HH + j]);
            float ain_b = __fmaf_rn(xb[t], wih[2 * HH + j], bin[j]);
            float ahn_b = bhn[j];
            #pragma unroll
            for (int k = 0; k < HH; ++k) {
                ar_a  = __fmaf_rn(whh[j][k],          ha[k], ar_a);
                ar_b  = __fmaf_rn(whh[j][k],          hb[k], ar_b);
                az_a  = __fmaf_rn(whh[HH + j][k],     ha[k], az_a);
                az_b  = __fmaf_rn(whh[HH + j][k],     hb[k], az_b);
                ahn_a = __fmaf_rn(whh[2 * HH + j][k], ha[k], ahn_a);
                ahn_b = __fmaf_rn(whh[2 * HH + j][k], hb[k], ahn_b);
            }
            float r_a  = sigmoidf_fast(ar_a);
            float r_b  = sigmoidf_fast(ar_b);
            float z_a  = sigmoidf_fast(az_a);
            float z_b  = sigmoidf_fast(az_b);
            float nv_a = tanhf_fast(__fmaf_rn(r_a, ahn_a, ain_a));
            float nv_b = tanhf_fast(__fmaf_rn(r_b, ahn_b, ain_b));
            // (1-z)*nv + z*h = z*(h - nv) + nv
            na[j] = __fmaf_rn(z_a, ha[j] - nv_a, nv_a);
            nb[j] = __fmaf_rn(z_b, hb[j] - nv_b, nv_b);
        }
        #pragma unroll
        for (int j = 0; j < HH; ++j) { ha[j] = na[j]; hb[j] = nb[j]; }
    }

    // y = fc(h) for both rows; out[(b*O + o)*S + s]
    float* op = out + (size_t)b0 * (OO * SS) + s;
    #pragma unroll
    for (int o = 0; o < OO; ++o) {
        float ya = fc_b[o];
        float yb = fc_b[o];
        #pragma unroll
        for (int k = 0; k < HH; ++k) {
            ya = __fmaf_rn(fc_w[o * HH + k], ha[k], ya);
            yb = __fmaf_rn(fc_w[o * HH + k], hb[k], yb);
        }
        op[o * SS] = ya;
        op[OO * SS + o * SS] = yb;   // row b0+1
    }
}

extern "C" void kernel_launch(void* const* d_in, const int* in_sizes, int n_in,
                              void* d_out, int out_size, void* d_ws, size_t ws_size,
                              hipStream_t stream) {
    const float* x    = (const float*)d_in[0];
    const float* w_ih = (const float*)d_in[1];
    const float* w_hh = (const float*)d_in[2];
    const float* b_ih = (const float*)d_in[3];
    const float* b_hh = (const float*)d_in[4];
    const float* fc_w = (const float*)d_in[5];
    const float* fc_b = (const float*)d_in[6];
    float* out = (float*)d_out;

    const int N = (BB / 2) * SS;               // 616,448 threads (2 rows each)
    const int block = 256;
    const int grid = (N + block - 1) / block;  // 2408 exactly
    gru_kernel<<<grid, block, 0, stream>>>(x, w_ih, w_hh, b_ih, b_hh, fc_w, fc_b, out);
}

// Round 6
// 158.339 us; speedup vs baseline: 1.2226x; 1.0271x over previous
//
#include <hip/hip_runtime.h>

#define BB 4096
#define TT 10
#define SS 301
#define HH 5
#define OO 3

// Raw v_rcp_f32 (~1 ulp) instead of IEEE div sequence.
__device__ __forceinline__ float fast_rcp(float x) {
    return __builtin_amdgcn_rcpf(x);
}
__device__ __forceinline__ float sigmoidf_fast(float x) {
    // 1/(1+e^-x); rcp(inf)=0 handles the saturated tail.
    return fast_rcp(1.0f + __expf(-x));
}
// overflow-safe tanh: 1 - 2/(e^{2x}+1); e->inf gives 1, e->0 gives -1
__device__ __forceinline__ float tanhf_fast(float x) {
    return __fmaf_rn(-2.0f, fast_rcp(__expf(2.0f * x) + 1.0f), 1.0f);
}

// __launch_bounds__(256, 2): min 2 waves/EU -> VGPR cap 256. We WANT a fat
// VGPR allocation: 110 weight values must stay resident. R0's 24-VGPR /
// 112-SGPR allocation couldn't hold them (SGPR file ~102), so the compiler
// reloaded/rematerialized weights inside the unrolled loop (~2x emitted
// instructions) -- the hidden cost this round removes.
__global__ __launch_bounds__(256, 2) void gru_kernel(
    const float* __restrict__ x,
    const float* __restrict__ w_ih,
    const float* __restrict__ w_hh,
    const float* __restrict__ b_ih,
    const float* __restrict__ b_hh,
    const float* __restrict__ fc_w,
    const float* __restrict__ fc_b,
    float* __restrict__ out)
{
    const int n = blockIdx.x * blockDim.x + threadIdx.x;
    const int b = n / SS;
    const int s = n - b * SS;
    if (b >= BB) return;

    float wih[3 * HH];
    float whh[3 * HH][HH];
    float brz[2 * HH];   // merged b_ih + b_hh for r,z gates
    float bin[HH];       // b_ih for n gate (outside r*)
    float bhn[HH];       // b_hh for n gate (inside r*)

    #pragma unroll
    for (int g = 0; g < 2 * HH; ++g) brz[g] = b_ih[g] + b_hh[g];
    #pragma unroll
    for (int j = 0; j < HH; ++j) {
        bin[j] = b_ih[2 * HH + j];
        bhn[j] = b_hh[2 * HH + j];
    }
    #pragma unroll
    for (int g = 0; g < 3 * HH; ++g) {
        wih[g] = w_ih[g];   // I == 1
        #pragma unroll
        for (int k = 0; k < HH; ++k) whh[g][k] = w_hh[g * HH + k];
    }

    // --- Pin every weight/bias into a VGPR, once. ---
    // The opaque asm makes the value unrematerializable; with the 256-VGPR
    // budget the allocator keeps all 110 resident, so every inner-loop FMA is
    // a single v_fma_f32 vD, vW, vH, vD (no SGPR pairs, no literals, no
    // reloads).
    #pragma unroll
    for (int g = 0; g < 3 * HH; ++g) {
        asm volatile("" : "+v"(wih[g]));
        #pragma unroll
        for (int k = 0; k < HH; ++k) asm volatile("" : "+v"(whh[g][k]));
    }
    #pragma unroll
    for (int g = 0; g < 2 * HH; ++g) asm volatile("" : "+v"(brz[g]));
    #pragma unroll
    for (int j = 0; j < HH; ++j) {
        asm volatile("" : "+v"(bin[j]));
        asm volatile("" : "+v"(bhn[j]));
    }

    // Preload all 10 inputs for this sample (coalesced across the wave per t).
    float xt[TT];
    const float* xp = x + (size_t)b * (TT * SS) + s;
    #pragma unroll
    for (int t = 0; t < TT; ++t) xt[t] = xp[t * SS];

    float h[HH];
    #pragma unroll
    for (int j = 0; j < HH; ++j) h[j] = 0.0f;

    #pragma unroll
    for (int t = 0; t < TT; ++t) {
        float hn[HH];
        #pragma unroll
        for (int j = 0; j < HH; ++j) {
            float ar  = __fmaf_rn(xt[t], wih[j],          brz[j]);
            float az  = __fmaf_rn(xt[t], wih[HH + j],     brz[HH + j]);
            float ain = __fmaf_rn(xt[t], wih[2 * HH + j], bin[j]);
            float ahn = bhn[j];
            #pragma unroll
            for (int k = 0; k < HH; ++k) {
                ar  = __fmaf_rn(whh[j][k],          h[k], ar);
                az  = __fmaf_rn(whh[HH + j][k],     h[k], az);
                ahn = __fmaf_rn(whh[2 * HH + j][k], h[k], ahn);
            }
            float r  = sigmoidf_fast(ar);
            float z  = sigmoidf_fast(az);
            float nv = tanhf_fast(__fmaf_rn(r, ahn, ain));
            // (1-z)*nv + z*h = z*(h - nv) + nv
            hn[j] = __fmaf_rn(z, h[j] - nv, nv);
        }
        #pragma unroll
        for (int j = 0; j < HH; ++j) h[j] = hn[j];
    }

    // y = fc(h); out[(b*O + o)*S + s]  (epilogue: load fc weights directly)
    float* op = out + (size_t)b * (OO * SS) + s;
    #pragma unroll
    for (int o = 0; o < OO; ++o) {
        float y = fc_b[o];
        #pragma unroll
        for (int k = 0; k < HH; ++k) y = __fmaf_rn(fc_w[o * HH + k], h[k], y);
        op[o * SS] = y;
    }
}

extern "C" void kernel_launch(void* const* d_in, const int* in_sizes, int n_in,
                              void* d_out, int out_size, void* d_ws, size_t ws_size,
                              hipStream_t stream) {
    const float* x    = (const float*)d_in[0];
    const float* w_ih = (const float*)d_in[1];
    const float* w_hh = (const float*)d_in[2];
    const float* b_ih = (const float*)d_in[3];
    const float* b_hh = (const float*)d_in[4];
    const float* fc_w = (const float*)d_in[5];
    const float* fc_b = (const float*)d_in[6];
    float* out = (float*)d_out;

    const int N = BB * SS;                 // 1,232,896
    const int block = 256;
    const int grid = (N + block - 1) / block;  // 4816 exactly
    gru_kernel<<<grid, block, 0, stream>>>(x, w_ih, w_hh, b_ih, b_hh, fc_w, fc_b, out);
}